// Round 1
// 457.008 us; speedup vs baseline: 1.0093x; 1.0093x over previous
//
#include <hip/hip_runtime.h>
#include <hip/hip_bf16.h>
#include <stdint.h>

#define B_ 8
#define L_ 8192
#define C_ 512

typedef short bf16x8 __attribute__((ext_vector_type(8)));
typedef float f32x4 __attribute__((ext_vector_type(4)));

#define GAS(p) ((const __attribute__((address_space(1))) void*)(p))
#define LAS(p) ((__attribute__((address_space(3))) void*)(p))

// ---------------- kernel 1: kv[b][c] = sum_l (k/||k||) * v ----------------
// 2048 blocks x 256 thr; block handles 32 rows of one batch (256 blocks/batch).
// Each wave owns 8 rows, processed as 2 phases of 4 rows with ALL loads (k and
// v) issued up front -> 16 KB in flight per wave (MLP fix for latency-bound
// baseline: 1.27 TB/s HBM, 3.8% VALUBusy).
__global__ __launch_bounds__(256)
void kv_reduce(const float* __restrict__ kin, const float* __restrict__ vin,
               float* __restrict__ kv) {
    const int bi   = blockIdx.x;
    const int b    = bi >> 8;             // 256 blocks per batch
    const int row0 = (bi & 255) * 32;
    const int lane = threadIdx.x & 63;
    const int wave = threadIdx.x >> 6;

    const float4* kb = (const float4*)(kin + ((size_t)b * L_ + row0) * C_);
    const float4* vb = (const float4*)(vin + ((size_t)b * L_ + row0) * C_);

    float4 acca = {0.f,0.f,0.f,0.f}, accb = {0.f,0.f,0.f,0.f};

    #pragma unroll 1
    for (int it = 0; it < 2; ++it) {
        const int r0 = wave * 8 + it * 4;
        float4 ka[4], kc[4], va[4], vc[4];
        // issue all 16 loads (4 rows x {k,v} x 2 chunks) before any use
        #pragma unroll
        for (int j = 0; j < 4; ++j) {
            const float4* krow = kb + (size_t)(r0 + j) * (C_/4);
            ka[j] = krow[lane];
            kc[j] = krow[64 + lane];
        }
        #pragma unroll
        for (int j = 0; j < 4; ++j) {
            const float4* vrow = vb + (size_t)(r0 + j) * (C_/4);
            va[j] = vrow[lane];
            vc[j] = vrow[64 + lane];
        }
        float ss[4];
        #pragma unroll
        for (int j = 0; j < 4; ++j)
            ss[j] = ka[j].x*ka[j].x + ka[j].y*ka[j].y + ka[j].z*ka[j].z + ka[j].w*ka[j].w
                  + kc[j].x*kc[j].x + kc[j].y*kc[j].y + kc[j].z*kc[j].z + kc[j].w*kc[j].w;
        // 4 independent butterfly chains -> pipelined through the DS unit
        #pragma unroll
        for (int m = 32; m >= 1; m >>= 1) {
            #pragma unroll
            for (int j = 0; j < 4; ++j) ss[j] += __shfl_xor(ss[j], m);
        }
        #pragma unroll
        for (int j = 0; j < 4; ++j) {
            const float inv = rsqrtf(ss[j]);
            acca.x += ka[j].x * inv * va[j].x;
            acca.y += ka[j].y * inv * va[j].y;
            acca.z += ka[j].z * inv * va[j].z;
            acca.w += ka[j].w * inv * va[j].w;
            accb.x += kc[j].x * inv * vc[j].x;
            accb.y += kc[j].y * inv * vc[j].y;
            accb.z += kc[j].z * inv * vc[j].z;
            accb.w += kc[j].w * inv * vc[j].w;
        }
    }

    // lane i holds channels 4i..4i+3 and 256+4i..256+4i+3
    __shared__ __align__(16) float red[4][C_];
    ((float4*)&red[wave][0])[lane]      = acca;
    ((float4*)&red[wave][0])[64 + lane] = accb;
    __syncthreads();
    for (int c = threadIdx.x; c < C_; c += 256) {
        float s = red[0][c] + red[1][c] + red[2][c] + red[3][c];
        atomicAdd(&kv[b * C_ + c], s);
    }
}

// ---------------- kernel 2: Wb[b][o][c] = bf16(kv[b][c] * W[o][c]) --------
__global__ __launch_bounds__(256)
void prep_w(const float* __restrict__ W, const float* __restrict__ kv,
            __hip_bfloat16* __restrict__ Wb) {
    int idx = blockIdx.x * 256 + threadIdx.x;   // 2048 blocks -> 2^19 threads
    int e   = idx << 2;                          // element in [b][o][c], c fast
    int b   = e >> 18;                           // 512*512 = 2^18 per batch
    int oc  = e & 0x3FFFF;
    int c   = oc & (C_ - 1);
    float4 w4 = *(const float4*)(W + oc);
    float4 s4 = *(const float4*)(kv + b * C_ + c);
    union { __hip_bfloat16 h[4]; uint2 u; } pk;
    pk.h[0] = __float2bfloat16(w4.x * s4.x);
    pk.h[1] = __float2bfloat16(w4.y * s4.y);
    pk.h[2] = __float2bfloat16(w4.z * s4.z);
    pk.h[3] = __float2bfloat16(w4.w * s4.w);
    *(uint2*)(Wb + e) = pk.u;
}

// ---------------- kernel 3: out = (1/||q_m||) * (q @ Wb^T) + bias ---------
// M=65536, N=512, K=512. BM=BN=128, BK=64, 256 thr = 2x2 waves of 64x64.
// LDS XOR-swizzle: element (row, k) lives at row*64 + ((k>>3)^(row&7))*8 + (k&7)
__global__ __launch_bounds__(256, 3)
void gemm_out(const float* __restrict__ qin, const __hip_bfloat16* __restrict__ Wb,
              const float* __restrict__ bias, float* __restrict__ out) {
    const int blk  = blockIdx.x;
    const int n0   = (blk & 3) * 128;
    const int m0   = (blk >> 2) * 128;
    const int b    = m0 >> 13;            // 8192 rows per batch, 128 | 8192
    const int tid  = threadIdx.x;
    const int lane = tid & 63;
    const int wave = tid >> 6;

    __shared__ __align__(16) unsigned short As[128 * 64];
    __shared__ __align__(16) unsigned short Bs[128 * 64];
    __shared__ float s_inv[128];

    const int aj  = tid & 7;              // k-chunk (8 bf16) within row
    const int arp = tid >> 3;             // 0..31 : row-in-pass
    const float* qbase = qin + (size_t)m0 * C_;
    const __hip_bfloat16* WbB = Wb + ((size_t)b * C_ + n0) * C_;

    const int r16 = lane & 15;
    const int qd  = lane >> 4;
    const int wm  = wave & 1;
    const int wn  = wave >> 1;

    f32x4 acc[4][4];
    #pragma unroll
    for (int i = 0; i < 4; ++i)
        #pragma unroll
        for (int j = 0; j < 4; ++j)
            acc[i][j] = (f32x4){0.f, 0.f, 0.f, 0.f};

    float ssq[4] = {0.f, 0.f, 0.f, 0.f};

    for (int kc = 0; kc < C_; kc += 64) {
        if (kc) __syncthreads();
        // ---- B tile (already bf16): async global->LDS, swizzled dest
        #pragma unroll
        for (int i = 0; i < 4; ++i) {
            int cid = i * 256 + wave * 64 + lane;     // 16B chunk id, 0..1023
            int n   = cid >> 3;
            int cj  = cid & 7;
            int kk  = ((cj ^ (n & 7)) << 3);
            const __hip_bfloat16* g = WbB + (size_t)n * C_ + kc + kk;
            __builtin_amdgcn_global_load_lds(GAS(g),
                LAS(&Bs[(i * 256 + wave * 64) * 8]), 16, 0, 0);
        }
        // ---- A tile: fp32 load + sumsq + bf16 convert + swizzled LDS store
        #pragma unroll
        for (int p = 0; p < 4; ++p) {
            int m = p * 32 + arp;
            const float* g = qbase + (size_t)m * C_ + kc + aj * 8;
            float4 x0 = ((const float4*)g)[0];
            float4 x1 = ((const float4*)g)[1];
            ssq[p] += x0.x*x0.x + x0.y*x0.y + x0.z*x0.z + x0.w*x0.w
                    + x1.x*x1.x + x1.y*x1.y + x1.z*x1.z + x1.w*x1.w;
            union { __hip_bfloat16 h[8]; uint4 u; } pk;
            pk.h[0] = __float2bfloat16(x0.x); pk.h[1] = __float2bfloat16(x0.y);
            pk.h[2] = __float2bfloat16(x0.z); pk.h[3] = __float2bfloat16(x0.w);
            pk.h[4] = __float2bfloat16(x1.x); pk.h[5] = __float2bfloat16(x1.y);
            pk.h[6] = __float2bfloat16(x1.z); pk.h[7] = __float2bfloat16(x1.w);
            *(uint4*)&As[m * 64 + ((aj ^ (m & 7)) << 3)] = pk.u;
        }
        __syncthreads();
        // ---- MFMA compute: 2 k-steps of 32, 4x4 tiles of 16x16
        #pragma unroll
        for (int ks = 0; ks < 2; ++ks) {
            bf16x8 af[4], bfr[4];
            #pragma unroll
            for (int t = 0; t < 4; ++t) {
                int m = wm * 64 + t * 16 + r16;
                af[t]  = *(const bf16x8*)&As[m * 64 + (((ks * 4 + qd) ^ (m & 7)) << 3)];
                int n = wn * 64 + t * 16 + r16;
                bfr[t] = *(const bf16x8*)&Bs[n * 64 + (((ks * 4 + qd) ^ (n & 7)) << 3)];
            }
            #pragma unroll
            for (int mt = 0; mt < 4; ++mt)
                #pragma unroll
                for (int nt = 0; nt < 4; ++nt)
                    acc[mt][nt] = __builtin_amdgcn_mfma_f32_16x16x32_bf16(
                        af[mt], bfr[nt], acc[mt][nt], 0, 0, 0);
        }
    }

    // ---- per-row inverse norm: reduce ssq across the 8 aj-threads per row
    #pragma unroll
    for (int p = 0; p < 4; ++p) {
        float s = ssq[p];
        s += __shfl_xor(s, 1);
        s += __shfl_xor(s, 2);
        s += __shfl_xor(s, 4);
        if (aj == 0) s_inv[p * 32 + arp] = rsqrtf(s);
    }
    __syncthreads();

    // ---- epilogue: scale by inv-norm, add bias, store fp32
    #pragma unroll
    for (int nt = 0; nt < 4; ++nt) {
        int col  = n0 + wn * 64 + nt * 16 + r16;
        float bv = bias[col];
        #pragma unroll
        for (int mt = 0; mt < 4; ++mt) {
            int rl = wm * 64 + mt * 16 + qd * 4;
            float4 inv4 = *(const float4*)&s_inv[rl];
            float* op = out + (size_t)(m0 + rl) * C_ + col;
            op[0]      = acc[mt][nt][0] * inv4.x + bv;
            op[C_]     = acc[mt][nt][1] * inv4.y + bv;
            op[2 * C_] = acc[mt][nt][2] * inv4.z + bv;
            op[3 * C_] = acc[mt][nt][3] * inv4.w + bv;
        }
    }
}

extern "C" void kernel_launch(void* const* d_in, const int* in_sizes, int n_in,
                              void* d_out, int out_size, void* d_ws, size_t ws_size,
                              hipStream_t stream) {
    const float* q    = (const float*)d_in[0];
    const float* k    = (const float*)d_in[1];
    const float* v    = (const float*)d_in[2];
    const float* W    = (const float*)d_in[3];
    const float* bias = (const float*)d_in[4];
    float* out = (float*)d_out;

    float* kv = (float*)d_ws;                                  // 8*512 fp32 = 16 KB
    __hip_bfloat16* Wb = (__hip_bfloat16*)((char*)d_ws + 16384); // 8*512*512 bf16 = 4 MB

    hipMemsetAsync(kv, 0, B_ * C_ * sizeof(float), stream);
    kv_reduce<<<2048, 256, 0, stream>>>(k, v, kv);
    prep_w<<<2048, 256, 0, stream>>>(W, kv, Wb);
    gemm_out<<<2048, 256, 0, stream>>>(q, Wb, bias, out);
}

// Round 2
// 418.161 us; speedup vs baseline: 1.1031x; 1.0929x over previous
//
#include <hip/hip_runtime.h>
#include <hip/hip_bf16.h>
#include <stdint.h>

#define B_ 8
#define L_ 8192
#define C_ 512

typedef short bf16x8 __attribute__((ext_vector_type(8)));
typedef float f32x4 __attribute__((ext_vector_type(4)));

#define GAS(p) ((const __attribute__((address_space(1))) void*)(p))
#define LAS(p) ((__attribute__((address_space(3))) void*)(p))

// ---------------- kernel 1: kv[b][c] = sum_l (k/||k||) * v ----------------
// 2048 blocks x 256 thr; block = 32 rows of one batch. Wave = 8 rows in 2
// phases of 4 (16 KB in flight). Loads are NONTEMPORAL: the k+v working set
// (268 MB) exceeds the 256 MB L3, so cached streaming thrashes (fill+evict
// per miss) and capped delivered BW at 2.6 TB/s in rounds 0-1. nt bypasses
// cache allocation.
__global__ __launch_bounds__(256)
void kv_reduce(const float* __restrict__ kin, const float* __restrict__ vin,
               float* __restrict__ kv) {
    const int bi   = blockIdx.x;
    const int b    = bi >> 8;             // 256 blocks per batch
    const int row0 = (bi & 255) * 32;
    const int lane = threadIdx.x & 63;
    const int wave = threadIdx.x >> 6;

    const f32x4* kb = (const f32x4*)(kin + ((size_t)b * L_ + row0) * C_);
    const f32x4* vb = (const f32x4*)(vin + ((size_t)b * L_ + row0) * C_);

    f32x4 acca = {0.f,0.f,0.f,0.f}, accb = {0.f,0.f,0.f,0.f};

    #pragma unroll 1
    for (int it = 0; it < 2; ++it) {
        const int r0 = wave * 8 + it * 4;
        f32x4 ka[4], kc[4], va[4], vc[4];
        // issue all 16 loads (4 rows x {k,v} x 2 chunks) before any use
        #pragma unroll
        for (int j = 0; j < 4; ++j) {
            const f32x4* krow = kb + (size_t)(r0 + j) * (C_/4);
            ka[j] = __builtin_nontemporal_load(krow + lane);
            kc[j] = __builtin_nontemporal_load(krow + 64 + lane);
        }
        #pragma unroll
        for (int j = 0; j < 4; ++j) {
            const f32x4* vrow = vb + (size_t)(r0 + j) * (C_/4);
            va[j] = __builtin_nontemporal_load(vrow + lane);
            vc[j] = __builtin_nontemporal_load(vrow + 64 + lane);
        }
        float ss[4];
        #pragma unroll
        for (int j = 0; j < 4; ++j)
            ss[j] = ka[j][0]*ka[j][0] + ka[j][1]*ka[j][1] + ka[j][2]*ka[j][2] + ka[j][3]*ka[j][3]
                  + kc[j][0]*kc[j][0] + kc[j][1]*kc[j][1] + kc[j][2]*kc[j][2] + kc[j][3]*kc[j][3];
        // 4 independent butterfly chains -> pipelined through the DS unit
        #pragma unroll
        for (int m = 32; m >= 1; m >>= 1) {
            #pragma unroll
            for (int j = 0; j < 4; ++j) ss[j] += __shfl_xor(ss[j], m);
        }
        #pragma unroll
        for (int j = 0; j < 4; ++j) {
            const float inv = rsqrtf(ss[j]);
            #pragma unroll
            for (int x = 0; x < 4; ++x) {
                acca[x] += ka[j][x] * inv * va[j][x];
                accb[x] += kc[j][x] * inv * vc[j][x];
            }
        }
    }

    // lane i holds channels 4i..4i+3 and 256+4i..256+4i+3
    __shared__ __align__(16) float red[4][C_];
    ((f32x4*)&red[wave][0])[lane]      = acca;
    ((f32x4*)&red[wave][0])[64 + lane] = accb;
    __syncthreads();
    for (int c = threadIdx.x; c < C_; c += 256) {
        float s = red[0][c] + red[1][c] + red[2][c] + red[3][c];
        atomicAdd(&kv[b * C_ + c], s);
    }
}

// ---------------- kernel 2: Wb[b][o][c] = bf16(kv[b][c] * W[o][c]) --------
__global__ __launch_bounds__(256)
void prep_w(const float* __restrict__ W, const float* __restrict__ kv,
            __hip_bfloat16* __restrict__ Wb) {
    int idx = blockIdx.x * 256 + threadIdx.x;   // 2048 blocks -> 2^19 threads
    int e   = idx << 2;                          // element in [b][o][c], c fast
    int b   = e >> 18;                           // 512*512 = 2^18 per batch
    int oc  = e & 0x3FFFF;
    int c   = oc & (C_ - 1);
    float4 w4 = *(const float4*)(W + oc);
    float4 s4 = *(const float4*)(kv + b * C_ + c);
    union { __hip_bfloat16 h[4]; uint2 u; } pk;
    pk.h[0] = __float2bfloat16(w4.x * s4.x);
    pk.h[1] = __float2bfloat16(w4.y * s4.y);
    pk.h[2] = __float2bfloat16(w4.z * s4.z);
    pk.h[3] = __float2bfloat16(w4.w * s4.w);
    *(uint2*)(Wb + e) = pk.u;
}

// ---------------- kernel 3: out = (1/||q_m||) * (q @ Wb^T) + bias ---------
// M=65536, N=512, K=512. BM=BN=128, BK=64, 256 thr = 2x2 waves of 64x64.
// LDS XOR-swizzle: element (row, k) lives at row*64 + ((k>>3)^(row&7))*8 + (k&7)
// Block remap for XCD L2 locality: the 4 N-blocks sharing an M-panel are
// placed on the SAME XCD (consecutive local index) so the 256 KB q panel is
// fetched from HBM once per panel instead of 4x.
__global__ __launch_bounds__(256, 3)
void gemm_out(const float* __restrict__ qin, const __hip_bfloat16* __restrict__ Wb,
              const float* __restrict__ bias, float* __restrict__ out) {
    const int blk   = blockIdx.x;
    const int xcd   = blk & 7;            // dispatch round-robins XCDs
    const int local = blk >> 3;           // 0..255 within this XCD
    const int n0    = (local & 3) * 128;
    const int m0    = (xcd * 64 + (local >> 2)) * 128;
    const int b     = m0 >> 13;           // 8192 rows per batch, 128 | 8192
    const int tid  = threadIdx.x;
    const int lane = tid & 63;
    const int wave = tid >> 6;

    __shared__ __align__(16) unsigned short As[128 * 64];
    __shared__ __align__(16) unsigned short Bs[128 * 64];
    __shared__ float s_inv[128];

    const int aj  = tid & 7;              // k-chunk (8 bf16) within row
    const int arp = tid >> 3;             // 0..31 : row-in-pass
    const float* qbase = qin + (size_t)m0 * C_;
    const __hip_bfloat16* WbB = Wb + ((size_t)b * C_ + n0) * C_;

    const int r16 = lane & 15;
    const int qd  = lane >> 4;
    const int wm  = wave & 1;
    const int wn  = wave >> 1;

    f32x4 acc[4][4];
    #pragma unroll
    for (int i = 0; i < 4; ++i)
        #pragma unroll
        for (int j = 0; j < 4; ++j)
            acc[i][j] = (f32x4){0.f, 0.f, 0.f, 0.f};

    float ssq[4] = {0.f, 0.f, 0.f, 0.f};

    for (int kc = 0; kc < C_; kc += 64) {
        if (kc) __syncthreads();
        // ---- B tile (already bf16): async global->LDS, swizzled dest
        #pragma unroll
        for (int i = 0; i < 4; ++i) {
            int cid = i * 256 + wave * 64 + lane;     // 16B chunk id, 0..1023
            int n   = cid >> 3;
            int cj  = cid & 7;
            int kk  = ((cj ^ (n & 7)) << 3);
            const __hip_bfloat16* g = WbB + (size_t)n * C_ + kc + kk;
            __builtin_amdgcn_global_load_lds(GAS(g),
                LAS(&Bs[(i * 256 + wave * 64) * 8]), 16, 0, 0);
        }
        // ---- A tile: fp32 load + sumsq + bf16 convert + swizzled LDS store
        #pragma unroll
        for (int p = 0; p < 4; ++p) {
            int m = p * 32 + arp;
            const float* g = qbase + (size_t)m * C_ + kc + aj * 8;
            float4 x0 = ((const float4*)g)[0];
            float4 x1 = ((const float4*)g)[1];
            ssq[p] += x0.x*x0.x + x0.y*x0.y + x0.z*x0.z + x0.w*x0.w
                    + x1.x*x1.x + x1.y*x1.y + x1.z*x1.z + x1.w*x1.w;
            union { __hip_bfloat16 h[8]; uint4 u; } pk;
            pk.h[0] = __float2bfloat16(x0.x); pk.h[1] = __float2bfloat16(x0.y);
            pk.h[2] = __float2bfloat16(x0.z); pk.h[3] = __float2bfloat16(x0.w);
            pk.h[4] = __float2bfloat16(x1.x); pk.h[5] = __float2bfloat16(x1.y);
            pk.h[6] = __float2bfloat16(x1.z); pk.h[7] = __float2bfloat16(x1.w);
            *(uint4*)&As[m * 64 + ((aj ^ (m & 7)) << 3)] = pk.u;
        }
        __syncthreads();
        // ---- MFMA compute: 2 k-steps of 32, 4x4 tiles of 16x16
        #pragma unroll
        for (int ks = 0; ks < 2; ++ks) {
            bf16x8 af[4], bfr[4];
            #pragma unroll
            for (int t = 0; t < 4; ++t) {
                int m = wm * 64 + t * 16 + r16;
                af[t]  = *(const bf16x8*)&As[m * 64 + (((ks * 4 + qd) ^ (m & 7)) << 3)];
                int n = wn * 64 + t * 16 + r16;
                bfr[t] = *(const bf16x8*)&Bs[n * 64 + (((ks * 4 + qd) ^ (n & 7)) << 3)];
            }
            #pragma unroll
            for (int mt = 0; mt < 4; ++mt)
                #pragma unroll
                for (int nt = 0; nt < 4; ++nt)
                    acc[mt][nt] = __builtin_amdgcn_mfma_f32_16x16x32_bf16(
                        af[mt], bfr[nt], acc[mt][nt], 0, 0, 0);
        }
    }

    // ---- per-row inverse norm: reduce ssq across the 8 aj-threads per row
    #pragma unroll
    for (int p = 0; p < 4; ++p) {
        float s = ssq[p];
        s += __shfl_xor(s, 1);
        s += __shfl_xor(s, 2);
        s += __shfl_xor(s, 4);
        if (aj == 0) s_inv[p * 32 + arp] = rsqrtf(s);
    }
    __syncthreads();

    // ---- epilogue: scale by inv-norm, add bias, store fp32
    #pragma unroll
    for (int nt = 0; nt < 4; ++nt) {
        int col  = n0 + wn * 64 + nt * 16 + r16;
        float bv = bias[col];
        #pragma unroll
        for (int mt = 0; mt < 4; ++mt) {
            int rl = wm * 64 + mt * 16 + qd * 4;
            float4 inv4 = *(const float4*)&s_inv[rl];
            float* op = out + (size_t)(m0 + rl) * C_ + col;
            op[0]      = acc[mt][nt][0] * inv4.x + bv;
            op[C_]     = acc[mt][nt][1] * inv4.y + bv;
            op[2 * C_] = acc[mt][nt][2] * inv4.z + bv;
            op[3 * C_] = acc[mt][nt][3] * inv4.w + bv;
        }
    }
}

extern "C" void kernel_launch(void* const* d_in, const int* in_sizes, int n_in,
                              void* d_out, int out_size, void* d_ws, size_t ws_size,
                              hipStream_t stream) {
    const float* q    = (const float*)d_in[0];
    const float* k    = (const float*)d_in[1];
    const float* v    = (const float*)d_in[2];
    const float* W    = (const float*)d_in[3];
    const float* bias = (const float*)d_in[4];
    float* out = (float*)d_out;

    float* kv = (float*)d_ws;                                  // 8*512 fp32 = 16 KB
    __hip_bfloat16* Wb = (__hip_bfloat16*)((char*)d_ws + 16384); // 8*512*512 bf16 = 4 MB

    hipMemsetAsync(kv, 0, B_ * C_ * sizeof(float), stream);
    kv_reduce<<<2048, 256, 0, stream>>>(k, v, kv);
    prep_w<<<2048, 256, 0, stream>>>(W, kv, Wb);
    gemm_out<<<2048, 256, 0, stream>>>(q, Wb, bias, out);
}